// Round 9
// baseline (202.094 us; speedup 1.0000x reference)
//
#include <hip/hip_runtime.h>
#include <stdint.h>

typedef __attribute__((ext_vector_type(8))) short short8;
typedef __attribute__((ext_vector_type(4))) float f32x4;

#define BIG 4.0f   // score shift: s' = BIG - 0.5||w||^2 + dot > 0 always

// fp32 -> bf16 bits, round-to-nearest-even
static __device__ __forceinline__ short f2bf(float f) {
    union { float f; uint32_t u; } v; v.f = f;
    uint32_t u = v.u;
    return (short)((u + 0x7FFFu + ((u >> 16) & 1u)) >> 16);
}

// ws layout:
//   ws[1] (u32)         : block-completion counter (zeroed by prep each launch)
//   ws[64 .. 64+2048)   : (BIG - 0.5*||w||^2) per code, group-major (4 x 512)
//   ws[4096 .. 4096+1024): per-block loss partials
//   byte 65536 + g*131072 : bf16 codebook for group g, FRAGMENT-MAJOR:
//       16B unit (nt 0..31, ks 0..3, lane 0..63) at ((nt*4+ks)*64 + lane)*16
//       lane = lh*16+lr holds code row nt*16+lr, dims [ks*32+lh*8, +8)

// Kernel 1: prep. 128 blocks x 256 threads; 16 lanes per code (coalesced).
__global__ void vq_prep_kernel(const float* __restrict__ w0, const float* __restrict__ w1,
                               const float* __restrict__ w2, const float* __restrict__ w3,
                               float* __restrict__ ws) {
    int tid = blockIdx.x * 256 + threadIdx.x;   // 0..32767
    if (tid == 0) ((unsigned*)ws)[1] = 0u;
    int code = tid >> 4;                        // 0..2047
    int u    = tid & 15;                        // dim unit (8 dims)
    int g = code >> 9, c = code & 511;
    int nt = c >> 4, lr = c & 15, ks = u >> 2, lh = u & 3;
    const float* wg = (g == 0) ? w0 : (g == 1) ? w1 : (g == 2) ? w2 : w3;
    const float* src = wg + (size_t)c * 128 + u * 8;
    float4 v0 = *(const float4*)(src);
    float4 v1 = *(const float4*)(src + 4);
    float s = v0.x*v0.x + v0.y*v0.y + v0.z*v0.z + v0.w*v0.w
            + v1.x*v1.x + v1.y*v1.y + v1.z*v1.z + v1.w*v1.w;
    short8 b;
    b[0] = f2bf(v0.x); b[1] = f2bf(v0.y); b[2] = f2bf(v0.z); b[3] = f2bf(v0.w);
    b[4] = f2bf(v1.x); b[5] = f2bf(v1.y); b[6] = f2bf(v1.z); b[7] = f2bf(v1.w);
    char* cb = (char*)ws + 65536 + (size_t)g * 131072;
    *(short8*)(cb + (size_t)(((nt * 4 + ks) * 64 + lh * 16 + lr) * 16)) = b;
    s += __shfl_xor(s, 1); s += __shfl_xor(s, 2);
    s += __shfl_xor(s, 4); s += __shfl_xor(s, 8);
    if (u == 0) ws[64 + code] = BIG - 0.5f * s;
}

// Kernel 2: main fused VQ. 1024 blocks (4/CU) x 256 threads (4 waves each,
// 16 waves/CU). NO codebook LDS staging: B-fragments stream from L2
// (codebook is L2-resident, fragment-major => perfectly coalesced).
// Waves fully independent; only a trivial early barrier for the norm table.
__global__ __launch_bounds__(256, 4)
void vq_main_kernel(const float* __restrict__ lat,
                    const float* __restrict__ w0, const float* __restrict__ w1,
                    const float* __restrict__ w2, const float* __restrict__ w3,
                    float* __restrict__ out, float* __restrict__ ws) {
    __shared__ float lwsq[512];    // BIG - 0.5*||w||^2
    __shared__ float slsum[4];
    __shared__ unsigned slast;

    const int bid   = blockIdx.x;            // 0..1023
    const int g     = bid >> 8;              // 0..3
    const int tbase = (bid & 255) * 128;     // token base within group token space
    const float* wg = (g == 0) ? w0 : (g == 1) ? w1 : (g == 2) ? w2 : w3;
    const char* cbg = (const char*)ws + 65536 + (size_t)g * 131072;

    const int t    = threadIdx.x;            // 0..255
    const int wave = t >> 6;                 // 0..3
    const int l    = t & 63;
    const int lr   = l & 15;
    const int lh   = l >> 4;
    const uint32_t invlr = 511 - lr;

    lwsq[t]       = ws[64 + g * 512 + t];
    lwsq[t + 256] = ws[64 + g * 512 + t + 256];

    // A fragments: 32 tokens/wave (mt=2), bf16 + fp32 xsq
    short8 afrag[2][4];
    float  xsq[2];
    const int wtok = tbase + wave * 32;
    #pragma unroll
    for (int mt = 0; mt < 2; mt++) {
        int token = wtok + mt * 16 + lr;
        const float* xp = lat + (size_t)token * 512 + g * 128 + lh * 8;
        float part = 0.f;
        #pragma unroll
        for (int ks = 0; ks < 4; ks++) {
            float4 v0 = *(const float4*)(xp + ks * 32);
            float4 v1 = *(const float4*)(xp + ks * 32 + 4);
            part += v0.x*v0.x + v0.y*v0.y + v0.z*v0.z + v0.w*v0.w
                  + v1.x*v1.x + v1.y*v1.y + v1.z*v1.z + v1.w*v1.w;
            short8 a;
            a[0] = f2bf(v0.x); a[1] = f2bf(v0.y); a[2] = f2bf(v0.z); a[3] = f2bf(v0.w);
            a[4] = f2bf(v1.x); a[5] = f2bf(v1.y); a[6] = f2bf(v1.z); a[7] = f2bf(v1.w);
            afrag[mt][ks] = a;
        }
        part += __shfl_xor(part, 16);
        part += __shfl_xor(part, 32);
        xsq[mt] = part;
    }

    __syncthreads();   // lwsq resident (only barrier)

    uint32_t rk[8];
    #pragma unroll
    for (int i = 0; i < 8; i++) rk[i] = 0u;

    // B streams from global (L2), 2 tiles in flight (register double-buffer)
    const char* bbase = cbg + (size_t)l * 16;
    short8 bA[4], bB[4];
    float  hA, hB;
    {
        const char* p0 = bbase;
        bA[0] = *(const short8*)(p0);
        bA[1] = *(const short8*)(p0 + 1024);
        bA[2] = *(const short8*)(p0 + 2048);
        bA[3] = *(const short8*)(p0 + 3072);
        hA = lwsq[lr];
        const char* p1 = bbase + 4096;
        bB[0] = *(const short8*)(p1);
        bB[1] = *(const short8*)(p1 + 1024);
        bB[2] = *(const short8*)(p1 + 2048);
        bB[3] = *(const short8*)(p1 + 3072);
        hB = lwsq[16 + lr];
    }

    for (int nt = 0; nt < 32; nt += 2) {
        // ---- tile nt (buffer A) ----
        {
            short8 c0 = bA[0], c1 = bA[1], c2 = bA[2], c3 = bA[3];
            float  hn = hA;
            const char* np = bbase + (size_t)((nt + 2) & 31) * 4096;
            bA[0] = *(const short8*)(np);
            bA[1] = *(const short8*)(np + 1024);
            bA[2] = *(const short8*)(np + 2048);
            bA[3] = *(const short8*)(np + 3072);
            hA = lwsq[(((nt + 2) & 31) << 4) + lr];
            const uint32_t invc = invlr - (uint32_t)(nt * 16);
            #pragma unroll
            for (int mt = 0; mt < 2; mt++) {
                f32x4 acc = {hn, hn, hn, hn};
                acc = __builtin_amdgcn_mfma_f32_16x16x32_bf16(afrag[mt][0], c0, acc, 0, 0, 0);
                acc = __builtin_amdgcn_mfma_f32_16x16x32_bf16(afrag[mt][1], c1, acc, 0, 0, 0);
                acc = __builtin_amdgcn_mfma_f32_16x16x32_bf16(afrag[mt][2], c2, acc, 0, 0, 0);
                acc = __builtin_amdgcn_mfma_f32_16x16x32_bf16(afrag[mt][3], c3, acc, 0, 0, 0);
                #pragma unroll
                for (int r = 0; r < 4; r++) {
                    uint32_t key = (__float_as_uint(acc[r]) & 0xFFFFFE00u) | invc;
                    rk[mt * 4 + r] = max(rk[mt * 4 + r], key);
                }
            }
        }
        // ---- tile nt+1 (buffer B) ----
        {
            short8 c0 = bB[0], c1 = bB[1], c2 = bB[2], c3 = bB[3];
            float  hn = hB;
            const char* np = bbase + (size_t)((nt + 3) & 31) * 4096;
            bB[0] = *(const short8*)(np);
            bB[1] = *(const short8*)(np + 1024);
            bB[2] = *(const short8*)(np + 2048);
            bB[3] = *(const short8*)(np + 3072);
            hB = lwsq[(((nt + 3) & 31) << 4) + lr];
            const uint32_t invc = invlr - (uint32_t)((nt + 1) * 16);
            #pragma unroll
            for (int mt = 0; mt < 2; mt++) {
                f32x4 acc = {hn, hn, hn, hn};
                acc = __builtin_amdgcn_mfma_f32_16x16x32_bf16(afrag[mt][0], c0, acc, 0, 0, 0);
                acc = __builtin_amdgcn_mfma_f32_16x16x32_bf16(afrag[mt][1], c1, acc, 0, 0, 0);
                acc = __builtin_amdgcn_mfma_f32_16x16x32_bf16(afrag[mt][2], c2, acc, 0, 0, 0);
                acc = __builtin_amdgcn_mfma_f32_16x16x32_bf16(afrag[mt][3], c3, acc, 0, 0, 0);
                #pragma unroll
                for (int r = 0; r < 4; r++) {
                    uint32_t key = (__float_as_uint(acc[r]) & 0xFFFFFE00u) | invc;
                    rk[mt * 4 + r] = max(rk[mt * 4 + r], key);
                }
            }
        }
    }

    // argmax across the 16 code-lanes (lr bits): plain u32 max reduce
    int runidx[8];
    #pragma unroll
    for (int i = 0; i < 8; i++) {
        uint32_t k = rk[i];
        k = max(k, (uint32_t)__shfl_xor((int)k, 1));
        k = max(k, (uint32_t)__shfl_xor((int)k, 2));
        k = max(k, (uint32_t)__shfl_xor((int)k, 4));
        k = max(k, (uint32_t)__shfl_xor((int)k, 8));
        rk[i] = k;
        runidx[i] = 511 - (int)(k & 0x1FFu);
    }

    // loss: dist = xsq + 2*BIG - 2*s'
    float lsum = 0.f;
    #pragma unroll
    for (int mt = 0; mt < 2; mt++) {
        #pragma unroll
        for (int r = 0; r < 4; r++) {
            int row = lh * 4 + r;
            float xs = __shfl(xsq[mt], (l & 48) | row);
            float val = __uint_as_float(rk[mt * 4 + r] & 0xFFFFFE00u);
            if (lr == 0) lsum += xs + 2.f * BIG - 2.f * val;
        }
    }
    lsum += __shfl_xor(lsum, 16);
    lsum += __shfl_xor(lsum, 32);
    if (l == 0) slsum[wave] = lsum;

    // q-write: 2 tokens/iter (lanes 0-31 / 32-63), 512B contiguous each
    #pragma unroll
    for (int it = 0; it < 16; it++) {
        const int j0 = it * 2, j1 = it * 2 + 1;
        int idx0 = __shfl(runidx[((j0 >> 4) << 2) | (j0 & 3)], ((j0 >> 2) & 3) << 4);
        int idx1 = __shfl(runidx[((j1 >> 4) << 2) | (j1 & 3)], ((j1 >> 2) & 3) << 4);
        int idx  = (l >= 32) ? idx1 : idx0;
        int tloc = it * 2 + (l >> 5);
        int col  = (l & 31) * 4;
        float4 v = *(const float4*)(wg + (size_t)idx * 128 + col);
        *(float4*)(out + (size_t)(wtok + tloc) * 512 + g * 128 + col) = v;
    }

    // loss: block partial -> last block reduces all 1024
    __syncthreads();
    if (t == 0) ws[4096 + bid] = slsum[0] + slsum[1] + slsum[2] + slsum[3];
    __threadfence();
    if (t == 0) slast = atomicAdd((unsigned*)ws + 1, 1u);
    __syncthreads();
    if (slast == 1023u) {
        __threadfence();
        float v = ws[4096 + t] + ws[4096 + 256 + t]
                + ws[4096 + 512 + t] + ws[4096 + 768 + t];
        #pragma unroll
        for (int m = 1; m < 64; m <<= 1) v += __shfl_xor(v, m);
        if (l == 0) slsum[wave] = v;
        __syncthreads();
        if (t == 0)
            out[16777216] = 1.25f * (slsum[0] + slsum[1] + slsum[2] + slsum[3])
                            * (1.0f / 4194304.0f);
    }
}

extern "C" void kernel_launch(void* const* d_in, const int* in_sizes, int n_in,
                              void* d_out, int out_size, void* d_ws, size_t ws_size,
                              hipStream_t stream) {
    const float* lat = (const float*)d_in[0];
    const float* w1  = (const float*)d_in[1];
    const float* w2  = (const float*)d_in[2];
    const float* w3  = (const float*)d_in[3];
    const float* w4  = (const float*)d_in[4];
    float* out = (float*)d_out;
    float* ws  = (float*)d_ws;

    vq_prep_kernel<<<128, 256, 0, stream>>>(w1, w2, w3, w4, ws);
    vq_main_kernel<<<1024, 256, 0, stream>>>(lat, w1, w2, w3, w4, out, ws);
}

// Round 10
// 43.945 us; speedup vs baseline: 4.5987x; 4.5987x over previous
//
#include <hip/hip_runtime.h>
#include <stdint.h>

typedef __attribute__((ext_vector_type(8))) short short8;
typedef __attribute__((ext_vector_type(4))) float f32x4;

#define BIG 4.0f   // score shift: s' = BIG - 0.5||w||^2 + dot > 0 always

// fp32 -> bf16 bits, round-to-nearest-even
static __device__ __forceinline__ short f2bf(float f) {
    union { float f; uint32_t u; } v; v.f = f;
    uint32_t u = v.u;
    return (short)((u + 0x7FFFu + ((u >> 16) & 1u)) >> 16);
}

static __device__ __forceinline__ void gload_lds16(const void* g, void* l) {
    __builtin_amdgcn_global_load_lds(
        (const __attribute__((address_space(1))) unsigned int*)g,
        (__attribute__((address_space(3))) unsigned int*)l, 16, 0, 0);
}

// ws layout:
//   ws[64 .. 64+2048)   : (BIG - 0.5*||w||^2) per code, group-major (4 x 512)
//   ws[4096 .. 4096+256): per-block loss partials
//   byte 65536 + g*131072 : bf16 codebook for group g, FRAGMENT-MAJOR:
//       16B unit (nt 0..31, ks 0..3, lane 0..63) at ((nt*4+ks)*64 + lane)*16
//       lane = lh*16+lr holds code row nt*16+lr, dims [ks*32+lh*8, +8)

// Kernel 1: prep. 128 blocks x 256 threads; 16 lanes per code (coalesced).
__global__ void vq_prep_kernel(const float* __restrict__ w0, const float* __restrict__ w1,
                               const float* __restrict__ w2, const float* __restrict__ w3,
                               float* __restrict__ ws) {
    int tid = blockIdx.x * 256 + threadIdx.x;   // 0..32767
    int code = tid >> 4;                        // 0..2047
    int u    = tid & 15;                        // dim unit (8 dims)
    int g = code >> 9, c = code & 511;
    int nt = c >> 4, lr = c & 15, ks = u >> 2, lh = u & 3;
    const float* wg = (g == 0) ? w0 : (g == 1) ? w1 : (g == 2) ? w2 : w3;
    const float* src = wg + (size_t)c * 128 + u * 8;
    float4 v0 = *(const float4*)(src);
    float4 v1 = *(const float4*)(src + 4);
    float s = v0.x*v0.x + v0.y*v0.y + v0.z*v0.z + v0.w*v0.w
            + v1.x*v1.x + v1.y*v1.y + v1.z*v1.z + v1.w*v1.w;
    short8 b;
    b[0] = f2bf(v0.x); b[1] = f2bf(v0.y); b[2] = f2bf(v0.z); b[3] = f2bf(v0.w);
    b[4] = f2bf(v1.x); b[5] = f2bf(v1.y); b[6] = f2bf(v1.z); b[7] = f2bf(v1.w);
    char* cb = (char*)ws + 65536 + (size_t)g * 131072;
    *(short8*)(cb + (size_t)(((nt * 4 + ks) * 64 + lh * 16 + lr) * 16)) = b;
    s += __shfl_xor(s, 1); s += __shfl_xor(s, 2);
    s += __shfl_xor(s, 4); s += __shfl_xor(s, 8);
    if (u == 0) ws[64 + code] = BIG - 0.5f * s;
}

// Kernel 2: main fused VQ. 256 blocks (1/CU) x 512 threads (8 waves, 2/SIMD).
// Full 128 KB codebook staged once; ONE barrier; each wave owns 64 tokens as
// two mt=2 batches with write-behind: batch-1 loads are issued before batch-0's
// epilogue so the q-write/gather overlaps the in-flight latent reads.
__global__ __launch_bounds__(512, 2)
void vq_main_kernel(const float* __restrict__ lat,
                    const float* __restrict__ w0, const float* __restrict__ w1,
                    const float* __restrict__ w2, const float* __restrict__ w3,
                    float* __restrict__ out, float* __restrict__ ws) {
    __shared__ __align__(16) short lw[65536];   // 128 KB codebook, fragment-major
    __shared__ float lwsq[512];                  // BIG - 0.5*||w||^2
    __shared__ float slsum[8];

    const int bid   = blockIdx.x;            // 0..255
    const int g     = bid >> 6;              // 0..3
    const int tbase = (bid & 63) * 512;      // token base within group token space
    const float* wg = (g == 0) ? w0 : (g == 1) ? w1 : (g == 2) ? w2 : w3;
    const char* cbg = (const char*)ws + 65536 + (size_t)g * 131072;

    const int t    = threadIdx.x;            // 0..511
    const int wave = t >> 6;                 // 0..7
    const int l    = t & 63;
    const int lr   = l & 15;
    const int lh   = l >> 4;
    const uint32_t invlr = 511 - lr;

    lwsq[t] = ws[64 + g * 512 + t];

    // stage full 128 KB codebook once: wave w owns bytes [w*16384, +16384)
    {
        const char* gsrc = cbg + wave * 16384 + l * 16;
        char* ldst = (char*)lw + wave * 16384;
        #pragma unroll
        for (int j = 0; j < 16; j++)
            gload_lds16(gsrc + j * 1024, ldst + j * 1024);
    }

    // batch-0 A fragments (32 tokens, mt=2): load+convert, overlaps codebook DMA
    auto load_convert = [&](short8 (&fr)[2][4], float (&xsp)[2], int wt) {
        #pragma unroll
        for (int mt = 0; mt < 2; mt++) {
            int token = wt + mt * 16 + lr;
            const float* xp = lat + (size_t)token * 512 + g * 128 + lh * 8;
            float part = 0.f;
            #pragma unroll
            for (int ks = 0; ks < 4; ks++) {
                float4 v0 = *(const float4*)(xp + ks * 32);
                float4 v1 = *(const float4*)(xp + ks * 32 + 4);
                part += v0.x*v0.x + v0.y*v0.y + v0.z*v0.z + v0.w*v0.w
                      + v1.x*v1.x + v1.y*v1.y + v1.z*v1.z + v1.w*v1.w;
                short8 a;
                a[0] = f2bf(v0.x); a[1] = f2bf(v0.y); a[2] = f2bf(v0.z); a[3] = f2bf(v0.w);
                a[4] = f2bf(v1.x); a[5] = f2bf(v1.y); a[6] = f2bf(v1.z); a[7] = f2bf(v1.w);
                fr[mt][ks] = a;
            }
            part += __shfl_xor(part, 16);
            part += __shfl_xor(part, 32);
            xsp[mt] = part;
        }
    };

    const char* lwb = (const char*)lw + l * 16;

    auto compute = [&](short8 (&af)[2][4], uint32_t (&rk)[8]) {
        short8 p0 = *(const short8*)(lwb);
        short8 p1 = *(const short8*)(lwb + 1024);
        short8 p2 = *(const short8*)(lwb + 2048);
        short8 p3 = *(const short8*)(lwb + 3072);
        float  ph = lwsq[lr];
        #pragma unroll 4
        for (int nt = 0; nt < 32; nt++) {
            short8 c0 = p0, c1 = p1, c2 = p2, c3 = p3;
            float  hn = ph;
            const char* nb = lwb + ((nt + 1) & 31) * 4096;
            p0 = *(const short8*)(nb);
            p1 = *(const short8*)(nb + 1024);
            p2 = *(const short8*)(nb + 2048);
            p3 = *(const short8*)(nb + 3072);
            ph = lwsq[(((nt + 1) & 31) << 4) + lr];
            const uint32_t invc = invlr - (uint32_t)(nt * 16);
            #pragma unroll
            for (int mt = 0; mt < 2; mt++) {
                f32x4 acc = {hn, hn, hn, hn};   // ends as BIG - 0.5||w||^2 + dot
                acc = __builtin_amdgcn_mfma_f32_16x16x32_bf16(af[mt][0], c0, acc, 0, 0, 0);
                acc = __builtin_amdgcn_mfma_f32_16x16x32_bf16(af[mt][1], c1, acc, 0, 0, 0);
                acc = __builtin_amdgcn_mfma_f32_16x16x32_bf16(af[mt][2], c2, acc, 0, 0, 0);
                acc = __builtin_amdgcn_mfma_f32_16x16x32_bf16(af[mt][3], c3, acc, 0, 0, 0);
                #pragma unroll
                for (int r = 0; r < 4; r++) {
                    uint32_t key = (__float_as_uint(acc[r]) & 0xFFFFFE00u) | invc;
                    rk[mt * 4 + r] = max(rk[mt * 4 + r], key);
                }
            }
        }
    };

    auto epilogue = [&](uint32_t (&rk)[8], float (&xsp)[2], int wt, float& acc_lsum) {
        int runidx[8];
        #pragma unroll
        for (int i = 0; i < 8; i++) {
            uint32_t k = rk[i];
            k = max(k, (uint32_t)__shfl_xor((int)k, 1));
            k = max(k, (uint32_t)__shfl_xor((int)k, 2));
            k = max(k, (uint32_t)__shfl_xor((int)k, 4));
            k = max(k, (uint32_t)__shfl_xor((int)k, 8));
            rk[i] = k;
            runidx[i] = 511 - (int)(k & 0x1FFu);
        }
        #pragma unroll
        for (int mt = 0; mt < 2; mt++) {
            #pragma unroll
            for (int r = 0; r < 4; r++) {
                int row = lh * 4 + r;
                float xs = __shfl(xsp[mt], (l & 48) | row);
                float val = __uint_as_float(rk[mt * 4 + r] & 0xFFFFFE00u);
                if (lr == 0) acc_lsum += xs + 2.f * BIG - 2.f * val;
            }
        }
        // q-write: 2 tokens/iter (lanes 0-31 / 32-63), 512B contiguous each
        #pragma unroll
        for (int it = 0; it < 16; it++) {
            const int j0 = it * 2, j1 = it * 2 + 1;
            int idx0 = __shfl(runidx[((j0 >> 4) << 2) | (j0 & 3)], ((j0 >> 2) & 3) << 4);
            int idx1 = __shfl(runidx[((j1 >> 4) << 2) | (j1 & 3)], ((j1 >> 2) & 3) << 4);
            int idx  = (l >= 32) ? idx1 : idx0;
            int tloc = it * 2 + (l >> 5);
            int col  = (l & 31) * 4;
            float4 v = *(const float4*)(wg + (size_t)idx * 128 + col);
            *(float4*)(out + (size_t)(wt + tloc) * 512 + g * 128 + col) = v;
        }
    };

    const int wtok = tbase + wave * 64;

    short8 fA[2][4], fB[2][4];
    float  xspA[2], xspB[2];
    uint32_t kA[8], kB[8];
    #pragma unroll
    for (int i = 0; i < 8; i++) { kA[i] = 0u; kB[i] = 0u; }

    load_convert(fA, xspA, wtok);        // overlaps codebook DMA
    __syncthreads();                     // codebook + lwsq resident (only barrier)

    float lsum = 0.f;
    compute(fA, kA);

    // ---- issue batch-1 raw loads; they fly during epilogue-0 ----
    float4 raw[16];
    #pragma unroll
    for (int mt = 0; mt < 2; mt++) {
        #pragma unroll
        for (int ks = 0; ks < 4; ks++) {
            const float* xp = lat + (size_t)(wtok + 32 + mt * 16 + lr) * 512
                            + g * 128 + lh * 8 + ks * 32;
            raw[mt * 8 + ks * 2]     = *(const float4*)(xp);
            raw[mt * 8 + ks * 2 + 1] = *(const float4*)(xp + 4);
        }
    }

    epilogue(kA, xspA, wtok, lsum);      // gather+write overlap raw-load flight

    // convert batch 1
    #pragma unroll
    for (int mt = 0; mt < 2; mt++) {
        float part = 0.f;
        #pragma unroll
        for (int ks = 0; ks < 4; ks++) {
            float4 v0 = raw[mt * 8 + ks * 2];
            float4 v1 = raw[mt * 8 + ks * 2 + 1];
            part += v0.x*v0.x + v0.y*v0.y + v0.z*v0.z + v0.w*v0.w
                  + v1.x*v1.x + v1.y*v1.y + v1.z*v1.z + v1.w*v1.w;
            short8 a;
            a[0] = f2bf(v0.x); a[1] = f2bf(v0.y); a[2] = f2bf(v0.z); a[3] = f2bf(v0.w);
            a[4] = f2bf(v1.x); a[5] = f2bf(v1.y); a[6] = f2bf(v1.z); a[7] = f2bf(v1.w);
            fB[mt][ks] = a;
        }
        part += __shfl_xor(part, 16);
        part += __shfl_xor(part, 32);
        xspB[mt] = part;
    }

    compute(fB, kB);
    epilogue(kB, xspB, wtok + 32, lsum);

    // loss: wave partial -> one plain store per block (no fence, no atomic)
    lsum += __shfl_xor(lsum, 16);
    lsum += __shfl_xor(lsum, 32);
    if (l == 0) slsum[wave] = lsum;
    __syncthreads();
    if (t == 0) {
        float s = 0.f;
        #pragma unroll
        for (int i = 0; i < 8; i++) s += slsum[i];
        ws[4096 + bid] = s;
    }
}

// Kernel 3: finalize loss — reduce 256 per-block partials
__global__ void vq_finalize_kernel(const float* __restrict__ ws, float* __restrict__ out) {
    __shared__ float s4[4];
    float v = ws[4096 + threadIdx.x];
    #pragma unroll
    for (int m = 1; m < 64; m <<= 1) v += __shfl_xor(v, m);
    if ((threadIdx.x & 63) == 0) s4[threadIdx.x >> 6] = v;
    __syncthreads();
    if (threadIdx.x == 0)
        out[16777216] = 1.25f * (s4[0] + s4[1] + s4[2] + s4[3]) * (1.0f / 4194304.0f);
}

extern "C" void kernel_launch(void* const* d_in, const int* in_sizes, int n_in,
                              void* d_out, int out_size, void* d_ws, size_t ws_size,
                              hipStream_t stream) {
    const float* lat = (const float*)d_in[0];
    const float* w1  = (const float*)d_in[1];
    const float* w2  = (const float*)d_in[2];
    const float* w3  = (const float*)d_in[3];
    const float* w4  = (const float*)d_in[4];
    float* out = (float*)d_out;
    float* ws  = (float*)d_ws;

    vq_prep_kernel<<<128, 256, 0, stream>>>(w1, w2, w3, w4, ws);
    vq_main_kernel<<<256, 512, 0, stream>>>(lat, w1, w2, w3, w4, out, ws);
    vq_finalize_kernel<<<1, 256, 0, stream>>>(ws, out);
}